// Round 16
// baseline (2197.433 us; speedup 1.0000x reference)
//
#include <hip/hip_runtime.h>
#include <hip/hip_bf16.h>
#include <math.h>

#define BATCH 32
#define TSEQ 1024
#define DMODEL 1024
#define KEXP 8
#define FFFN 4096
#define EEMB 64
#define RHID 128
#define NSTAGE 5
#define NVIEW 4

typedef float f32x4 __attribute__((ext_vector_type(4)));
typedef __bf16 bf16x8 __attribute__((ext_vector_type(8)));

#define AS1C(p) ((const __attribute__((address_space(1))) unsigned int*)(p))
#define AS3(p)  ((__attribute__((address_space(3))) unsigned int*)(p))

__device__ __forceinline__ unsigned short f32_to_bf16_rne(float f) {
    union { float f; unsigned int u; } v; v.f = f;
    unsigned int u = v.u;
    unsigned int r = u + 0x7FFFu + ((u >> 16) & 1u);
    return (unsigned short)(r >> 16);
}

__device__ void resolve_ids_r16(const int* __restrict__ raw, int* __restrict__ out, int hi) {
    bool is64 = true;
    for (int i = 1; i < 32; i += 2) is64 = is64 && (raw[i] == 0);
    for (int i = 0; i < 32; i += 2) is64 = is64 && (raw[i] >= 0 && raw[i] < hi);
    for (int b = 0; b < BATCH; ++b) {
        int v = is64 ? raw[2 * b] : raw[b];
        v = v < 0 ? 0 : (v >= hi ? hi - 1 : v);
        out[b] = v;
    }
}

// ------------- router: fp64 exact, 4 samples in parallel (512 threads) -------------
__global__ __launch_bounds__(512) void router_r16(
    const int* __restrict__ stage_ids,
    const int* __restrict__ view_ids,
    const float* __restrict__ stage_emb,
    const float* __restrict__ view_emb,
    const float* __restrict__ rw1,
    const float* __restrict__ rb1,
    const float* __restrict__ rw2,
    const float* __restrict__ rb2,
    float* __restrict__ out_probs,
    float* __restrict__ out_sel,
    float* __restrict__ out_loss,
    int* __restrict__ sel_ws)
{
    __shared__ int sids[BATCH], vids[BATCH];
    __shared__ double z[4][2 * EEMB];
    __shared__ double h[4][RHID];
    __shared__ double lg[4][KEXP];
    __shared__ double Psum[4][KEXP];
    __shared__ int fcount[4][KEXP];
    const int t = threadIdx.x;
    const int g = t >> 7;        // sample group 0..3
    const int u = t & 127;
    if (t == 0) {
        resolve_ids_r16(stage_ids, sids, NSTAGE);
        resolve_ids_r16(view_ids, vids, NVIEW);
    }
    if (u < KEXP) { Psum[g][u] = 0.0; fcount[g][u] = 0; }
    __syncthreads();

    for (int b0 = 0; b0 < BATCH; b0 += 4) {
        const int b = b0 + g;
        const int sid = sids[b], vid = vids[b];
        z[g][u] = (u < EEMB) ? (double)stage_emb[sid * EEMB + u]
                             : (double)view_emb[vid * EEMB + (u - EEMB)];
        __syncthreads();
        double acc = (double)rb1[u];
        for (int i = 0; i < 2 * EEMB; ++i) acc += z[g][i] * (double)rw1[i * RHID + u];
        h[g][u] = fmax(acc, 0.0);
        __syncthreads();
        if (u < KEXP) {
            double a = (double)rb2[u];
            for (int i = 0; i < RHID; ++i) a += h[g][i] * (double)rw2[i * KEXP + u];
            lg[g][u] = a;
        }
        __syncthreads();
        if (u == 0) {
            double mx = lg[g][0]; int am = 0;
            for (int k = 1; k < KEXP; ++k) if (lg[g][k] > mx) { mx = lg[g][k]; am = k; }
            double p[KEXP]; double den = 0.0;
            for (int k = 0; k < KEXP; ++k) { p[k] = exp(lg[g][k] - mx); den += p[k]; }
            for (int k = 0; k < KEXP; ++k) {
                double pk = p[k] / den;
                out_probs[b * KEXP + k] = (float)pk;
                Psum[g][k] += pk;
            }
            out_sel[b] = (float)am;
            sel_ws[b] = am;
            fcount[g][am] += 1;
        }
        __syncthreads();
    }
    if (t == 0) {
        double loss = 0.0;
        for (int k = 0; k < KEXP; ++k) {
            double ps = Psum[0][k] + Psum[1][k] + Psum[2][k] + Psum[3][k];
            int fc = fcount[0][k] + fcount[1][k] + fcount[2][k] + fcount[3][k];
            loss += ((double)fc / (double)BATCH) * (ps / (double)BATCH);
        }
        out_loss[0] = (float)((double)KEXP * loss);
    }
}

// ---------------- prep: f32 -> bf16 convert (x) ----------------
__global__ void cvt_f32_bf16_r16(const float* __restrict__ src,
                                 unsigned short* __restrict__ dst, size_t n)
{
    size_t i = (size_t)blockIdx.x * blockDim.x + threadIdx.x;
    size_t stride = (size_t)gridDim.x * blockDim.x;
    for (size_t j = i * 4; j < n; j += stride * 4) {
        float4 v = *(const float4*)(src + j);
        ushort4 o;
        o.x = f32_to_bf16_rne(v.x); o.y = f32_to_bf16_rne(v.y);
        o.z = f32_to_bf16_rne(v.z); o.w = f32_to_bf16_rne(v.w);
        *(ushort4*)(dst + j) = o;
    }
}

// ------ prep: 64x64 tiled transpose+convert src[e][R][C] f32 -> dst[e][C][R] bf16 ------
// (64,8) threads; reads 256B/wave-row coalesced; writes 128B/wave (64 x bf16);
// LDS stride 65 -> conflict-free on both sides.
__global__ __launch_bounds__(512) void transpose_f32_bf16_r16(
    const float* __restrict__ src, unsigned short* __restrict__ dst, int R, int C)
{
    __shared__ float tile[64][65];
    const int e = blockIdx.z;
    const float* s = src + (size_t)e * R * C;
    unsigned short* d = dst + (size_t)e * R * C;
    const int c0 = blockIdx.x * 64, r0 = blockIdx.y * 64;
    const int tx = threadIdx.x, ty = threadIdx.y; // (64, 8)
    #pragma unroll
    for (int i = 0; i < 64; i += 8)
        tile[ty + i][tx] = s[(size_t)(r0 + ty + i) * C + (c0 + tx)];
    __syncthreads();
    #pragma unroll
    for (int i = 0; i < 64; i += 8)
        d[(size_t)(c0 + ty + i) * R + (r0 + tx)] = f32_to_bf16_rne(tile[tx][ty + i]);
}

// ====== m97-structure + zero-conflict swizzle: 128x128 / BK=64 / 4-wave GEMM ======
// Frozen from r15 (390us, 705 TF, 0 conflicts); only launch_bounds 4->5 blocks/CU.

#define BM 128
#define BN 128
#define BK 64

template<int MODE, int OBF>  // MODE 0: gelu(acc+bias); 1: acc+bias. OBF: 1 bf16 out, 0 f32 out
__global__ __launch_bounds__(256, 5) void gemm_bt_r16(
    const unsigned short* __restrict__ Aall,
    const unsigned short* __restrict__ BTall,
    const float* __restrict__ biasAll,
    void* __restrict__ OutV,
    const int* __restrict__ sel, int g0,
    int M, int N, int K)
{
    const int bz = blockIdx.z;
    int e = sel[g0 + bz];
    e = e < 0 ? 0 : (e >= KEXP ? KEXP - 1 : e);
    const unsigned short* A  = Aall + (size_t)bz * M * K;
    const unsigned short* BT = BTall + (size_t)e * (size_t)N * K;
    const float* bias = biasAll + (size_t)e * N;

    __shared__ __align__(16) unsigned short As[BM][BK];   // 16 KB, rows 128B (8 chunks)
    __shared__ __align__(16) unsigned short Bs[BN][BK];   // 16 KB

    const int tid  = threadIdx.x;
    const int lane = tid & 63;
    const int wave = tid >> 6;     // 0..3
    const int wr = wave >> 1;
    const int wc = wave & 1;
    const int fr = lane & 15;
    const int fq = lane >> 4;
    const int swz = fr & 7;        // read-side row-XOR (row&7 == fr&7)

    const int brow = blockIdx.y * BM;
    const int bcol = blockIdx.x * BN;

    const int srow = lane >> 3;                          // 0..7
    const int scol = ((lane & 7) ^ (lane >> 3)) * 8;     // pre-swizzled source chunk

    const f32x4 zero = {0.f, 0.f, 0.f, 0.f};
    f32x4 acc[4][4];
    #pragma unroll
    for (int m = 0; m < 4; ++m)
        #pragma unroll
        for (int n = 0; n < 4; ++n) acc[m][n] = zero;

    for (int k0 = 0; k0 < K; k0 += BK) {
        #pragma unroll
        for (int i = 0; i < 4; ++i) {
            const int r0 = i * 32 + wave * 8;
            const unsigned short* gA = A + (size_t)(brow + r0 + srow) * K + (k0 + scol);
            __builtin_amdgcn_global_load_lds(AS1C(gA), AS3(&As[r0][0]), 16, 0, 0);
        }
        #pragma unroll
        for (int i = 0; i < 4; ++i) {
            const int r0 = i * 32 + wave * 8;
            const unsigned short* gB = BT + (size_t)(bcol + r0 + srow) * K + (k0 + scol);
            __builtin_amdgcn_global_load_lds(AS1C(gB), AS3(&Bs[r0][0]), 16, 0, 0);
        }
        __syncthreads();

        bf16x8 af[4][2], bfr[4][2];
        #pragma unroll
        for (int m = 0; m < 4; ++m) {
            const int ra = wr * 64 + m * 16 + fr;
            #pragma unroll
            for (int ks = 0; ks < 2; ++ks) {
                const int ch = (ks * 4 + fq) ^ swz;
                af[m][ks] = *(const bf16x8*)(&As[ra][ch * 8]);
            }
        }
        #pragma unroll
        for (int n = 0; n < 4; ++n) {
            const int rb = wc * 64 + n * 16 + fr;
            #pragma unroll
            for (int ks = 0; ks < 2; ++ks) {
                const int ch = (ks * 4 + fq) ^ swz;
                bfr[n][ks] = *(const bf16x8*)(&Bs[rb][ch * 8]);
            }
        }

        #pragma unroll
        for (int ks = 0; ks < 2; ++ks)
            #pragma unroll
            for (int m = 0; m < 4; ++m)
                #pragma unroll
                for (int n = 0; n < 4; ++n)
                    acc[m][n] = __builtin_amdgcn_mfma_f32_16x16x32_bf16(af[m][ks], bfr[n][ks], acc[m][n], 0, 0, 0);

        __syncthreads();
    }

    // epilogue: C/D col=lane&15, row=(lane>>4)*4+reg  [HW-verified rounds 8-15]
    #pragma unroll
    for (int m = 0; m < 4; ++m) {
        #pragma unroll
        for (int n = 0; n < 4; ++n) {
            #pragma unroll
            for (int r = 0; r < 4; ++r) {
                const int row = brow + wr * 64 + m * 16 + fq * 4 + r;
                const int col = bcol + wc * 64 + n * 16 + fr;
                float v = acc[m][n][r] + bias[col];
                if (MODE == 0) v = 0.5f * v * (1.0f + erff(v * 0.70710678118654752f));
                const size_t idx = (size_t)bz * M * N + (size_t)row * N + col;
                if (OBF) ((unsigned short*)OutV)[idx] = f32_to_bf16_rne(v);
                else     ((float*)OutV)[idx] = v;
            }
        }
    }
}

extern "C" void kernel_launch(void* const* d_in, const int* in_sizes, int n_in,
                              void* d_out, int out_size, void* d_ws, size_t ws_size,
                              hipStream_t stream)
{
    const float* x         = (const float*)d_in[0];
    const int*   stage_ids = (const int*)d_in[1];
    const int*   view_ids  = (const int*)d_in[2];
    const float* stage_emb = (const float*)d_in[3];
    const float* view_emb  = (const float*)d_in[4];
    const float* rw1       = (const float*)d_in[5];
    const float* rb1       = (const float*)d_in[6];
    const float* rw2       = (const float*)d_in[7];
    const float* rb2       = (const float*)d_in[8];
    const float* w1        = (const float*)d_in[9];
    const float* b1        = (const float*)d_in[10];
    const float* w2        = (const float*)d_in[11];
    const float* b2        = (const float*)d_in[12];

    float* out_f = (float*)d_out;
    const size_t OUT_ELEMS = (size_t)BATCH * TSEQ * DMODEL;

    // ws layout: [4KB hdr][x_bf 64MB][w1T 64MB][w2T 64MB][h grp*8MB]
    const size_t MB64 = 67108864ull;
    char* ws = (char*)d_ws;
    int* sel_ws            = (int*)ws;
    unsigned short* x_bf   = (unsigned short*)(ws + 4096);
    unsigned short* w1T    = (unsigned short*)(ws + 4096 + MB64);
    unsigned short* w2T    = (unsigned short*)(ws + 4096 + 2 * MB64);
    unsigned short* h_bf   = (unsigned short*)(ws + 4096 + 3 * MB64);

    int grp = 1;
    {
        const size_t base = 4096 + 3 * MB64;
        const size_t avail = ws_size > base ? ws_size - base : 0;
        for (int g = 32; g >= 1; g >>= 1) {
            if ((size_t)g * TSEQ * FFFN * 2 <= avail) { grp = g; break; }
        }
    }

    router_r16<<<1, 512, 0, stream>>>(stage_ids, view_ids, stage_emb, view_emb,
        rw1, rb1, rw2, rb2,
        out_f + OUT_ELEMS,
        out_f + OUT_ELEMS + BATCH * KEXP,
        out_f + OUT_ELEMS + BATCH * KEXP + BATCH,
        sel_ws);

    cvt_f32_bf16_r16<<<2048, 256, 0, stream>>>(x, x_bf, (size_t)BATCH * TSEQ * DMODEL);
    dim3 tb(64, 8);
    // w1 [8][1024][4096] -> w1T [8][4096][1024]
    transpose_f32_bf16_r16<<<dim3(FFFN / 64, DMODEL / 64, KEXP), tb, 0, stream>>>(w1, w1T, DMODEL, FFFN);
    // w2 [8][4096][1024] -> w2T [8][1024][4096]
    transpose_f32_bf16_r16<<<dim3(DMODEL / 64, FFFN / 64, KEXP), tb, 0, stream>>>(w2, w2T, FFFN, DMODEL);

    for (int g0 = 0; g0 < BATCH; g0 += grp) {
        // h = gelu(x @ w1[e]^T + b1[e]) : M=1024, N=4096, K=1024 -> bf16
        gemm_bt_r16<0, 1><<<dim3(FFFN / BN, TSEQ / BM, grp), 256, 0, stream>>>(
            x_bf + (size_t)g0 * TSEQ * DMODEL, w1T, b1,
            (void*)h_bf, sel_ws, g0, TSEQ, FFFN, DMODEL);
        // out = h @ w2[e]^T + b2[e]     : M=1024, N=1024, K=4096 -> f32
        gemm_bt_r16<1, 0><<<dim3(DMODEL / BN, TSEQ / BM, grp), 256, 0, stream>>>(
            h_bf, w2T, b2,
            (void*)(out_f + (size_t)g0 * TSEQ * DMODEL), sel_ws, g0, TSEQ, DMODEL, FFFN);
    }
}

// Round 17
// 887.332 us; speedup vs baseline: 2.4764x; 2.4764x over previous
//
#include <hip/hip_runtime.h>
#include <hip/hip_bf16.h>
#include <math.h>

#define BATCH 32
#define TSEQ 1024
#define DMODEL 1024
#define KEXP 8
#define FFFN 4096
#define EEMB 64
#define RHID 128
#define NSTAGE 5
#define NVIEW 4

typedef float f32x4 __attribute__((ext_vector_type(4)));
typedef __bf16 bf16x8 __attribute__((ext_vector_type(8)));

#define AS1C(p) ((const __attribute__((address_space(1))) unsigned int*)(p))
#define AS3(p)  ((__attribute__((address_space(3))) unsigned int*)(p))

__device__ __forceinline__ unsigned short f32_to_bf16_rne(float f) {
    union { float f; unsigned int u; } v; v.f = f;
    unsigned int u = v.u;
    unsigned int r = u + 0x7FFFu + ((u >> 16) & 1u);
    return (unsigned short)(r >> 16);
}

__device__ void resolve_ids_r17(const int* __restrict__ raw, int* __restrict__ out, int hi) {
    bool is64 = true;
    for (int i = 1; i < 32; i += 2) is64 = is64 && (raw[i] == 0);
    for (int i = 0; i < 32; i += 2) is64 = is64 && (raw[i] >= 0 && raw[i] < hi);
    for (int b = 0; b < BATCH; ++b) {
        int v = is64 ? raw[2 * b] : raw[b];
        v = v < 0 ? 0 : (v >= hi ? hi - 1 : v);
        out[b] = v;
    }
}

// ------------- router: fp64 exact, 4 samples in parallel (512 threads) -------------
__global__ __launch_bounds__(512) void router_r17(
    const int* __restrict__ stage_ids,
    const int* __restrict__ view_ids,
    const float* __restrict__ stage_emb,
    const float* __restrict__ view_emb,
    const float* __restrict__ rw1,
    const float* __restrict__ rb1,
    const float* __restrict__ rw2,
    const float* __restrict__ rb2,
    float* __restrict__ out_probs,
    float* __restrict__ out_sel,
    float* __restrict__ out_loss,
    int* __restrict__ sel_ws)
{
    __shared__ int sids[BATCH], vids[BATCH];
    __shared__ double z[4][2 * EEMB];
    __shared__ double h[4][RHID];
    __shared__ double lg[4][KEXP];
    __shared__ double Psum[4][KEXP];
    __shared__ int fcount[4][KEXP];
    const int t = threadIdx.x;
    const int g = t >> 7;        // sample group 0..3
    const int u = t & 127;
    if (t == 0) {
        resolve_ids_r17(stage_ids, sids, NSTAGE);
        resolve_ids_r17(view_ids, vids, NVIEW);
    }
    if (u < KEXP) { Psum[g][u] = 0.0; fcount[g][u] = 0; }
    __syncthreads();

    for (int b0 = 0; b0 < BATCH; b0 += 4) {
        const int b = b0 + g;
        const int sid = sids[b], vid = vids[b];
        z[g][u] = (u < EEMB) ? (double)stage_emb[sid * EEMB + u]
                             : (double)view_emb[vid * EEMB + (u - EEMB)];
        __syncthreads();
        double acc = (double)rb1[u];
        for (int i = 0; i < 2 * EEMB; ++i) acc += z[g][i] * (double)rw1[i * RHID + u];
        h[g][u] = fmax(acc, 0.0);
        __syncthreads();
        if (u < KEXP) {
            double a = (double)rb2[u];
            for (int i = 0; i < RHID; ++i) a += h[g][i] * (double)rw2[i * KEXP + u];
            lg[g][u] = a;
        }
        __syncthreads();
        if (u == 0) {
            double mx = lg[g][0]; int am = 0;
            for (int k = 1; k < KEXP; ++k) if (lg[g][k] > mx) { mx = lg[g][k]; am = k; }
            double p[KEXP]; double den = 0.0;
            for (int k = 0; k < KEXP; ++k) { p[k] = exp(lg[g][k] - mx); den += p[k]; }
            for (int k = 0; k < KEXP; ++k) {
                double pk = p[k] / den;
                out_probs[b * KEXP + k] = (float)pk;
                Psum[g][k] += pk;
            }
            out_sel[b] = (float)am;
            sel_ws[b] = am;
            fcount[g][am] += 1;
        }
        __syncthreads();
    }
    if (t == 0) {
        double loss = 0.0;
        for (int k = 0; k < KEXP; ++k) {
            double ps = Psum[0][k] + Psum[1][k] + Psum[2][k] + Psum[3][k];
            int fc = fcount[0][k] + fcount[1][k] + fcount[2][k] + fcount[3][k];
            loss += ((double)fc / (double)BATCH) * (ps / (double)BATCH);
        }
        out_loss[0] = (float)((double)KEXP * loss);
    }
}

// ---------------- prep: f32 -> bf16 convert (x) ----------------
__global__ void cvt_f32_bf16_r17(const float* __restrict__ src,
                                 unsigned short* __restrict__ dst, size_t n)
{
    size_t i = (size_t)blockIdx.x * blockDim.x + threadIdx.x;
    size_t stride = (size_t)gridDim.x * blockDim.x;
    for (size_t j = i * 4; j < n; j += stride * 4) {
        float4 v = *(const float4*)(src + j);
        ushort4 o;
        o.x = f32_to_bf16_rne(v.x); o.y = f32_to_bf16_rne(v.y);
        o.z = f32_to_bf16_rne(v.z); o.w = f32_to_bf16_rne(v.w);
        *(ushort4*)(dst + j) = o;
    }
}

// ------ prep: 64x64 tiled transpose+convert src[e][R][C] f32 -> dst[e][C][R] bf16 ------
__global__ __launch_bounds__(512) void transpose_f32_bf16_r17(
    const float* __restrict__ src, unsigned short* __restrict__ dst, int R, int C)
{
    __shared__ float tile[64][65];
    const int e = blockIdx.z;
    const float* s = src + (size_t)e * R * C;
    unsigned short* d = dst + (size_t)e * R * C;
    const int c0 = blockIdx.x * 64, r0 = blockIdx.y * 64;
    const int tx = threadIdx.x, ty = threadIdx.y; // (64, 8)
    #pragma unroll
    for (int i = 0; i < 64; i += 8)
        tile[ty + i][tx] = s[(size_t)(r0 + ty + i) * C + (c0 + tx)];
    __syncthreads();
    #pragma unroll
    for (int i = 0; i < 64; i += 8)
        d[(size_t)(c0 + ty + i) * R + (r0 + tx)] = f32_to_bf16_rne(tile[tx][ty + i]);
}

// ====== m97-structure + zero-conflict swizzle: 128x128 / BK=64 / 4-wave GEMM ======
// Byte-exact r15 configuration (390us/dispatch, 705 TF, 0 conflicts, VGPR=64,
// 4 blocks/CU). launch_bounds MUST stay (256,4): (256,5) capped VGPR at 48 ->
// accumulator spill -> 1.96GB scratch writes -> 2.7x regression (r16).

#define BM 128
#define BN 128
#define BK 64

template<int MODE, int OBF>  // MODE 0: gelu(acc+bias); 1: acc+bias. OBF: 1 bf16 out, 0 f32 out
__global__ __launch_bounds__(256, 4) void gemm_bt_r17(
    const unsigned short* __restrict__ Aall,
    const unsigned short* __restrict__ BTall,
    const float* __restrict__ biasAll,
    void* __restrict__ OutV,
    const int* __restrict__ sel, int g0,
    int M, int N, int K)
{
    const int bz = blockIdx.z;
    int e = sel[g0 + bz];
    e = e < 0 ? 0 : (e >= KEXP ? KEXP - 1 : e);
    const unsigned short* A  = Aall + (size_t)bz * M * K;
    const unsigned short* BT = BTall + (size_t)e * (size_t)N * K;
    const float* bias = biasAll + (size_t)e * N;

    __shared__ __align__(16) unsigned short As[BM][BK];   // 16 KB, rows 128B (8 chunks)
    __shared__ __align__(16) unsigned short Bs[BN][BK];   // 16 KB

    const int tid  = threadIdx.x;
    const int lane = tid & 63;
    const int wave = tid >> 6;     // 0..3
    const int wr = wave >> 1;
    const int wc = wave & 1;
    const int fr = lane & 15;
    const int fq = lane >> 4;
    const int swz = fr & 7;        // read-side row-XOR (row&7 == fr&7)

    const int brow = blockIdx.y * BM;
    const int bcol = blockIdx.x * BN;

    const int srow = lane >> 3;                          // 0..7
    const int scol = ((lane & 7) ^ (lane >> 3)) * 8;     // pre-swizzled source chunk

    const f32x4 zero = {0.f, 0.f, 0.f, 0.f};
    f32x4 acc[4][4];
    #pragma unroll
    for (int m = 0; m < 4; ++m)
        #pragma unroll
        for (int n = 0; n < 4; ++n) acc[m][n] = zero;

    for (int k0 = 0; k0 < K; k0 += BK) {
        #pragma unroll
        for (int i = 0; i < 4; ++i) {
            const int r0 = i * 32 + wave * 8;
            const unsigned short* gA = A + (size_t)(brow + r0 + srow) * K + (k0 + scol);
            __builtin_amdgcn_global_load_lds(AS1C(gA), AS3(&As[r0][0]), 16, 0, 0);
        }
        #pragma unroll
        for (int i = 0; i < 4; ++i) {
            const int r0 = i * 32 + wave * 8;
            const unsigned short* gB = BT + (size_t)(bcol + r0 + srow) * K + (k0 + scol);
            __builtin_amdgcn_global_load_lds(AS1C(gB), AS3(&Bs[r0][0]), 16, 0, 0);
        }
        __syncthreads();

        bf16x8 af[4][2], bfr[4][2];
        #pragma unroll
        for (int m = 0; m < 4; ++m) {
            const int ra = wr * 64 + m * 16 + fr;
            #pragma unroll
            for (int ks = 0; ks < 2; ++ks) {
                const int ch = (ks * 4 + fq) ^ swz;
                af[m][ks] = *(const bf16x8*)(&As[ra][ch * 8]);
            }
        }
        #pragma unroll
        for (int n = 0; n < 4; ++n) {
            const int rb = wc * 64 + n * 16 + fr;
            #pragma unroll
            for (int ks = 0; ks < 2; ++ks) {
                const int ch = (ks * 4 + fq) ^ swz;
                bfr[n][ks] = *(const bf16x8*)(&Bs[rb][ch * 8]);
            }
        }

        #pragma unroll
        for (int ks = 0; ks < 2; ++ks)
            #pragma unroll
            for (int m = 0; m < 4; ++m)
                #pragma unroll
                for (int n = 0; n < 4; ++n)
                    acc[m][n] = __builtin_amdgcn_mfma_f32_16x16x32_bf16(af[m][ks], bfr[n][ks], acc[m][n], 0, 0, 0);

        __syncthreads();
    }

    // epilogue: C/D col=lane&15, row=(lane>>4)*4+reg  [HW-verified rounds 8-16]
    #pragma unroll
    for (int m = 0; m < 4; ++m) {
        #pragma unroll
        for (int n = 0; n < 4; ++n) {
            #pragma unroll
            for (int r = 0; r < 4; ++r) {
                const int row = brow + wr * 64 + m * 16 + fq * 4 + r;
                const int col = bcol + wc * 64 + n * 16 + fr;
                float v = acc[m][n][r] + bias[col];
                if (MODE == 0) v = 0.5f * v * (1.0f + erff(v * 0.70710678118654752f));
                const size_t idx = (size_t)bz * M * N + (size_t)row * N + col;
                if (OBF) ((unsigned short*)OutV)[idx] = f32_to_bf16_rne(v);
                else     ((float*)OutV)[idx] = v;
            }
        }
    }
}

extern "C" void kernel_launch(void* const* d_in, const int* in_sizes, int n_in,
                              void* d_out, int out_size, void* d_ws, size_t ws_size,
                              hipStream_t stream)
{
    const float* x         = (const float*)d_in[0];
    const int*   stage_ids = (const int*)d_in[1];
    const int*   view_ids  = (const int*)d_in[2];
    const float* stage_emb = (const float*)d_in[3];
    const float* view_emb  = (const float*)d_in[4];
    const float* rw1       = (const float*)d_in[5];
    const float* rb1       = (const float*)d_in[6];
    const float* rw2       = (const float*)d_in[7];
    const float* rb2       = (const float*)d_in[8];
    const float* w1        = (const float*)d_in[9];
    const float* b1        = (const float*)d_in[10];
    const float* w2        = (const float*)d_in[11];
    const float* b2        = (const float*)d_in[12];

    float* out_f = (float*)d_out;
    const size_t OUT_ELEMS = (size_t)BATCH * TSEQ * DMODEL;

    // ws layout: [4KB hdr][x_bf 64MB][w1T 64MB][w2T 64MB][h grp*8MB]
    const size_t MB64 = 67108864ull;
    char* ws = (char*)d_ws;
    int* sel_ws            = (int*)ws;
    unsigned short* x_bf   = (unsigned short*)(ws + 4096);
    unsigned short* w1T    = (unsigned short*)(ws + 4096 + MB64);
    unsigned short* w2T    = (unsigned short*)(ws + 4096 + 2 * MB64);
    unsigned short* h_bf   = (unsigned short*)(ws + 4096 + 3 * MB64);

    int grp = 1;
    {
        const size_t base = 4096 + 3 * MB64;
        const size_t avail = ws_size > base ? ws_size - base : 0;
        for (int g = 32; g >= 1; g >>= 1) {
            if ((size_t)g * TSEQ * FFFN * 2 <= avail) { grp = g; break; }
        }
    }

    router_r17<<<1, 512, 0, stream>>>(stage_ids, view_ids, stage_emb, view_emb,
        rw1, rb1, rw2, rb2,
        out_f + OUT_ELEMS,
        out_f + OUT_ELEMS + BATCH * KEXP,
        out_f + OUT_ELEMS + BATCH * KEXP + BATCH,
        sel_ws);

    cvt_f32_bf16_r17<<<2048, 256, 0, stream>>>(x, x_bf, (size_t)BATCH * TSEQ * DMODEL);
    dim3 tb(64, 8);
    // w1 [8][1024][4096] -> w1T [8][4096][1024]
    transpose_f32_bf16_r17<<<dim3(FFFN / 64, DMODEL / 64, KEXP), tb, 0, stream>>>(w1, w1T, DMODEL, FFFN);
    // w2 [8][4096][1024] -> w2T [8][1024][4096]
    transpose_f32_bf16_r17<<<dim3(DMODEL / 64, FFFN / 64, KEXP), tb, 0, stream>>>(w2, w2T, FFFN, DMODEL);

    for (int g0 = 0; g0 < BATCH; g0 += grp) {
        // h = gelu(x @ w1[e]^T + b1[e]) : M=1024, N=4096, K=1024 -> bf16
        gemm_bt_r17<0, 1><<<dim3(FFFN / BN, TSEQ / BM, grp), 256, 0, stream>>>(
            x_bf + (size_t)g0 * TSEQ * DMODEL, w1T, b1,
            (void*)h_bf, sel_ws, g0, TSEQ, FFFN, DMODEL);
        // out = h @ w2[e]^T + b2[e]     : M=1024, N=1024, K=4096 -> f32
        gemm_bt_r17<1, 0><<<dim3(DMODEL / BN, TSEQ / BM, grp), 256, 0, stream>>>(
            h_bf, w2T, b2,
            (void*)(out_f + (size_t)g0 * TSEQ * DMODEL), sel_ws, g0, TSEQ, DMODEL, FFFN);
    }
}